// Round 1
// baseline (594.675 us; speedup 1.0000x reference)
//
#include <hip/hip_runtime.h>
#include <math.h>

// RoutingLayer: routing = x@w_gate + noise*(softplus(x@w_noise)+0.01);
// out = scatter(softmax(top2(routing)))
// x: 32768x2048 fp32, w_gate/w_noise: 2048x64 fp32, noise: 32768x64 fp32
// out: 32768x64 fp32.
// Compute-bound fp32 vector GEMM (no fp32 MFMA on CDNA4): 17.2 GF / 157 TF
// => ~110us floor. Fused epilogue.

constexpr int DIMK = 2048;
constexpr int NEXP = 64;
constexpr int BM = 128;   // rows per block
constexpr int BN = 128;   // 64 gate cols ++ 64 noise cols
constexpr int BK = 32;
constexpr int TM = 8;
constexpr int TN = 8;
constexpr int NTHREADS = 256;
constexpr int NKT = DIMK / BK;

__global__ __launch_bounds__(NTHREADS)
void routing_kernel(const float* __restrict__ x,
                    const float* __restrict__ wg,
                    const float* __restrict__ wn,
                    const float* __restrict__ noise,
                    float* __restrict__ out)
{
    __shared__ float As[BK][BM + 4];      // +4 pad: conflict-free b128 reads at fixed k
    __shared__ float Bs[BK][BN];
    __shared__ float R[BM][NEXP + 1];     // routing values, stride 65 (odd) for scan
    __shared__ float g1s[BM], g2s[BM];
    __shared__ int   i1s[BM], i2s[BM];

    const int tid = threadIdx.x;
    const int tx = tid & 15;              // 16 col-groups of TN=8
    const int ty = tid >> 4;              // 16 row-groups of TM=8
    const int row0 = blockIdx.x * BM;

    float acc[TM][TN] = {};

    // A staging: 1024 float4s (128 rows x 8 k-quads); thread does 4
    const int a_k4  = tid & 7;            // k-quad within BK (0..7)
    const int a_row = tid >> 3;           // row (0..31), +i*32
    // B staging: 1024 float4s (32 k-rows x 32 col-quads); thread does 4
    const int b_c4  = tid & 31;           // col-quad (0..31): <16 gate, >=16 noise
    const int b_kr  = tid >> 5;           // k-row (0..7), +i*8

    const float* b_src_base = (b_c4 < 16) ? (wg + b_c4 * 4)
                                          : (wn + (b_c4 - 16) * 4);

    float4 ra[4], rb[4];

#define LOAD_TILE(k0)                                                          \
    do {                                                                       \
        _Pragma("unroll")                                                      \
        for (int i = 0; i < 4; ++i)                                            \
            ra[i] = *reinterpret_cast<const float4*>(                          \
                x + (size_t)(row0 + a_row + i * 32) * DIMK + (k0) + a_k4 * 4); \
        _Pragma("unroll")                                                      \
        for (int i = 0; i < 4; ++i)                                            \
            rb[i] = *reinterpret_cast<const float4*>(                          \
                b_src_base + (size_t)((k0) + b_kr + i * 8) * NEXP);            \
    } while (0)

    LOAD_TILE(0);

    for (int kt = 0; kt < NKT; ++kt) {
        // regs -> LDS (A transposed to k-major)
        #pragma unroll
        for (int i = 0; i < 4; ++i) {
            int row = a_row + i * 32;
            As[a_k4 * 4 + 0][row] = ra[i].x;
            As[a_k4 * 4 + 1][row] = ra[i].y;
            As[a_k4 * 4 + 2][row] = ra[i].z;
            As[a_k4 * 4 + 3][row] = ra[i].w;
        }
        #pragma unroll
        for (int i = 0; i < 4; ++i)
            *reinterpret_cast<float4*>(&Bs[b_kr + i * 8][b_c4 * 4]) = rb[i];
        __syncthreads();

        // prefetch next tile while computing this one (hides HBM latency)
        if (kt + 1 < NKT) LOAD_TILE((kt + 1) * BK);

        #pragma unroll 8
        for (int k = 0; k < BK; ++k) {
            float4 a0 = *reinterpret_cast<const float4*>(&As[k][ty * TM]);
            float4 a1 = *reinterpret_cast<const float4*>(&As[k][ty * TM + 4]);
            float4 b0 = *reinterpret_cast<const float4*>(&Bs[k][tx * TN]);
            float4 b1 = *reinterpret_cast<const float4*>(&Bs[k][tx * TN + 4]);
            float av[TM] = {a0.x, a0.y, a0.z, a0.w, a1.x, a1.y, a1.z, a1.w};
            float bv[TN] = {b0.x, b0.y, b0.z, b0.w, b1.x, b1.y, b1.z, b1.w};
            #pragma unroll
            for (int i = 0; i < TM; ++i)
                #pragma unroll
                for (int j = 0; j < TN; ++j)
                    acc[i][j] = fmaf(av[i], bv[j], acc[i][j]);
        }
        __syncthreads();
    }
#undef LOAD_TILE

    // ---- epilogue ----
    // noise cols (tx>=8): R[row][e] = noise * (softplus(acc)+0.01)
    if (tx >= 8) {
        #pragma unroll
        for (int i = 0; i < TM; ++i) {
            int row = ty * TM + i;
            const float* nptr = noise + (size_t)(row0 + row) * NEXP + (tx - 8) * TN;
            float4 n0 = *reinterpret_cast<const float4*>(nptr);
            float4 n1 = *reinterpret_cast<const float4*>(nptr + 4);
            float nv[8] = {n0.x, n0.y, n0.z, n0.w, n1.x, n1.y, n1.z, n1.w};
            #pragma unroll
            for (int j = 0; j < TN; ++j) {
                float v = acc[i][j];
                float sp = fmaxf(v, 0.f) + log1pf(expf(-fabsf(v)));
                R[row][(tx - 8) * TN + j] = nv[j] * (sp + 0.01f);
            }
        }
    }
    __syncthreads();
    // gate cols (tx<8): R += gate dot products
    if (tx < 8) {
        #pragma unroll
        for (int i = 0; i < TM; ++i) {
            int row = ty * TM + i;
            #pragma unroll
            for (int j = 0; j < TN; ++j)
                R[row][tx * TN + j] += acc[i][j];
        }
    }
    __syncthreads();

    // per-row top-2 (strict > keeps the earliest index on ties, matching
    // jax.lax.top_k lower-index-first) + 2-way softmax
    if (tid < BM) {
        const int row = tid;
        float v1 = -INFINITY, v2 = -INFINITY;
        int i1 = 0, i2 = 0;
        #pragma unroll
        for (int e = 0; e < NEXP; ++e) {
            float v = R[row][e];
            if (v > v1)      { v2 = v1; i2 = i1; v1 = v; i1 = e; }
            else if (v > v2) { v2 = v; i2 = e; }
        }
        float t  = expf(v2 - v1);      // <= 1, no overflow
        float g1 = 1.f / (1.f + t);
        g1s[row] = g1;
        g2s[row] = t * g1;
        i1s[row] = i1;
        i2s[row] = i2;
    }
    __syncthreads();

    // scatter: write the full 128x64 out tile (zeros + two gates per row)
    #pragma unroll
    for (int u = 0; u < (BM * NEXP / 4) / NTHREADS; ++u) {   // 8 iters
        int f   = u * NTHREADS + tid;
        int row = f >> 4;
        int e0  = (f & 15) * 4;
        int i1 = i1s[row], i2 = i2s[row];
        float g1 = g1s[row], g2 = g2s[row];
        float4 o;
        o.x = (e0 + 0 == i1) ? g1 : ((e0 + 0 == i2) ? g2 : 0.f);
        o.y = (e0 + 1 == i1) ? g1 : ((e0 + 1 == i2) ? g2 : 0.f);
        o.z = (e0 + 2 == i1) ? g1 : ((e0 + 2 == i2) ? g2 : 0.f);
        o.w = (e0 + 3 == i1) ? g1 : ((e0 + 3 == i2) ? g2 : 0.f);
        *reinterpret_cast<float4*>(out + (size_t)(row0 + row) * NEXP + e0) = o;
    }
}

extern "C" void kernel_launch(void* const* d_in, const int* in_sizes, int n_in,
                              void* d_out, int out_size, void* d_ws, size_t ws_size,
                              hipStream_t stream) {
    const float* x     = (const float*)d_in[0];
    const float* wg    = (const float*)d_in[1];
    const float* wn    = (const float*)d_in[2];
    const float* noise = (const float*)d_in[3];
    float* out = (float*)d_out;

    const int Brows = in_sizes[0] / DIMK;      // 32768
    dim3 grid(Brows / BM);                     // 256 blocks -> 1 per CU
    routing_kernel<<<grid, NTHREADS, 0, stream>>>(x, wg, wn, noise, out);
}

// Round 2
// 566.135 us; speedup vs baseline: 1.0504x; 1.0504x over previous
//
#include <hip/hip_runtime.h>
#include <math.h>

// RoutingLayer fused: routing = x@w_gate + noise*(softplus(x@w_noise)+0.01);
// out = scatter(softmax(top2(routing)))
// x: 32768x2048 fp32, w_gate/w_noise: 2048x64, noise: 32768x64, out: 32768x64.
//
// R2: occupancy fix. BM=64, 512 blocks -> 2 blocks/CU = 8 waves/CU (was 1
// wave/SIMD). Per-thread tile 4 rows x (4 gate + 4 noise cols of the SAME
// 4 experts) -> B reads are quad-stride (2-way bank alias = free, was 4-way
// conflict), and the epilogue (combine + top-2 + softmax + scatter) is fully
// register/shuffle-based - no LDS R array, no epilogue barriers.

constexpr int DIMK = 2048;
constexpr int NEXP = 64;
constexpr int BM = 64;    // rows per block
constexpr int BN = 128;   // 64 gate cols ++ 64 noise cols
constexpr int BK = 32;
constexpr int TM = 4;     // rows per thread
constexpr int NTHREADS = 256;
constexpr int NKT = DIMK / BK;

__device__ __forceinline__ bool gt_pair(float a, int ia, float b, int ib) {
    // "a beats b" with jax top_k tie-break (lower index wins on equal value)
    return (a > b) || (a == b && ia < ib);
}

__global__ __launch_bounds__(NTHREADS)
void routing_kernel(const float* __restrict__ x,
                    const float* __restrict__ wg,
                    const float* __restrict__ wn,
                    const float* __restrict__ noise,
                    float* __restrict__ out)
{
    __shared__ float As[BK][BM + 4];   // k-major A; +4 pad
    __shared__ float Bs[BK][BN];       // [k][0..63]=gate, [64..127]=noise

    const int tid = threadIdx.x;
    const int tx = tid & 15;           // expert-quad selector (experts 4tx..4tx+3)
    const int ty = tid >> 4;           // row-group (0..15), rows ty*4..ty*4+3
    const int row0 = blockIdx.x * BM;

    float accg[TM][4] = {};            // gate accumulators
    float accn[TM][4] = {};            // noise accumulators

    // A staging: 512 float4s (64 rows x 8 k-quads); 2 per thread
    const int a_k4  = tid & 7;         // k-quad (0..7)
    const int a_row = tid >> 3;        // row (0..31), +i*32
    // B staging: 1024 float4s (32 k-rows x 32 col-quads); 4 per thread
    const int b_c4  = tid & 31;        // col-quad: <16 gate, >=16 noise
    const int b_kr  = tid >> 5;        // k-row (0..7), +i*8

    const float* b_src_base = (b_c4 < 16) ? (wg + b_c4 * 4)
                                          : (wn + (b_c4 - 16) * 4);

    float4 ra[2], rb[4];

#define LOAD_TILE(k0)                                                          \
    do {                                                                       \
        _Pragma("unroll")                                                      \
        for (int i = 0; i < 2; ++i)                                            \
            ra[i] = *reinterpret_cast<const float4*>(                          \
                x + (size_t)(row0 + a_row + i * 32) * DIMK + (k0) + a_k4 * 4); \
        _Pragma("unroll")                                                      \
        for (int i = 0; i < 4; ++i)                                            \
            rb[i] = *reinterpret_cast<const float4*>(                          \
                b_src_base + (size_t)((k0) + b_kr + i * 8) * NEXP);            \
    } while (0)

    LOAD_TILE(0);

    for (int kt = 0; kt < NKT; ++kt) {
        #pragma unroll
        for (int i = 0; i < 2; ++i) {
            int row = a_row + i * 32;
            As[a_k4 * 4 + 0][row] = ra[i].x;
            As[a_k4 * 4 + 1][row] = ra[i].y;
            As[a_k4 * 4 + 2][row] = ra[i].z;
            As[a_k4 * 4 + 3][row] = ra[i].w;
        }
        #pragma unroll
        for (int i = 0; i < 4; ++i)
            *reinterpret_cast<float4*>(&Bs[b_kr + i * 8][b_c4 * 4]) = rb[i];
        __syncthreads();

        if (kt + 1 < NKT) LOAD_TILE((kt + 1) * BK);   // reg prefetch over compute

        #pragma unroll 8
        for (int k = 0; k < BK; ++k) {
            float4 a  = *reinterpret_cast<const float4*>(&As[k][ty * TM]);
            float4 bg = *reinterpret_cast<const float4*>(&Bs[k][tx * 4]);
            float4 bn = *reinterpret_cast<const float4*>(&Bs[k][NEXP + tx * 4]);
            float av[TM] = {a.x, a.y, a.z, a.w};
            float gv[4]  = {bg.x, bg.y, bg.z, bg.w};
            float nv[4]  = {bn.x, bn.y, bn.z, bn.w};
            #pragma unroll
            for (int i = 0; i < TM; ++i) {
                #pragma unroll
                for (int j = 0; j < 4; ++j) {
                    accg[i][j] = fmaf(av[i], gv[j], accg[i][j]);
                    accn[i][j] = fmaf(av[i], nv[j], accn[i][j]);
                }
            }
        }
        __syncthreads();
    }
#undef LOAD_TILE

    // ---- register/shuffle epilogue: per thread, 4 rows x experts 4tx..4tx+3
    #pragma unroll
    for (int i = 0; i < TM; ++i) {
        const int row = row0 + ty * TM + i;
        float4 nz = *reinterpret_cast<const float4*>(noise + (size_t)row * NEXP + tx * 4);
        float nzv[4] = {nz.x, nz.y, nz.z, nz.w};
        float r[4];
        #pragma unroll
        for (int j = 0; j < 4; ++j) {
            float v = accn[i][j];
            float sp = fmaxf(v, 0.f) + log1pf(expf(-fabsf(v)));
            r[j] = accg[i][j] + nzv[j] * (sp + 0.01f);
        }
        // local top-2 over this thread's 4 experts (ascending id, strict >)
        float v1 = -INFINITY, v2 = -INFINITY;
        int i1 = 0, i2 = 0;
        #pragma unroll
        for (int j = 0; j < 4; ++j) {
            int e = tx * 4 + j;
            if (r[j] > v1)      { v2 = v1; i2 = i1; v1 = r[j]; i1 = e; }
            else if (r[j] > v2) { v2 = r[j]; i2 = e; }
        }
        // merge across the 16 tx-lanes (partners share ty, so masks 1,2,4,8)
        #pragma unroll
        for (int m = 1; m <= 8; m <<= 1) {
            float b1 = __shfl_xor(v1, m);
            int  ib1 = __shfl_xor(i1, m);
            float b2 = __shfl_xor(v2, m);
            int  ib2 = __shfl_xor(i2, m);
            if (gt_pair(b1, ib1, v1, i1)) {
                float o1 = v1; int oi1 = i1;
                v1 = b1; i1 = ib1;
                if (gt_pair(b2, ib2, o1, oi1)) { v2 = b2; i2 = ib2; }
                else                           { v2 = o1; i2 = oi1; }
            } else {
                if (gt_pair(b1, ib1, v2, i2)) { v2 = b1; i2 = ib1; }
            }
        }
        // 2-way softmax and coalesced scatter of this thread's 4 experts
        float t  = expf(v2 - v1);        // <= 1
        float g1 = 1.f / (1.f + t);
        float g2 = t * g1;
        float4 o;
        o.x = (tx * 4 + 0 == i1) ? g1 : ((tx * 4 + 0 == i2) ? g2 : 0.f);
        o.y = (tx * 4 + 1 == i1) ? g1 : ((tx * 4 + 1 == i2) ? g2 : 0.f);
        o.z = (tx * 4 + 2 == i1) ? g1 : ((tx * 4 + 2 == i2) ? g2 : 0.f);
        o.w = (tx * 4 + 3 == i1) ? g1 : ((tx * 4 + 3 == i2) ? g2 : 0.f);
        *reinterpret_cast<float4*>(out + (size_t)row * NEXP + tx * 4) = o;
    }
}

extern "C" void kernel_launch(void* const* d_in, const int* in_sizes, int n_in,
                              void* d_out, int out_size, void* d_ws, size_t ws_size,
                              hipStream_t stream) {
    const float* x     = (const float*)d_in[0];
    const float* wg    = (const float*)d_in[1];
    const float* wn    = (const float*)d_in[2];
    const float* noise = (const float*)d_in[3];
    float* out = (float*)d_out;

    const int Brows = in_sizes[0] / DIMK;      // 32768
    dim3 grid(Brows / BM);                     // 512 blocks -> 2 per CU
    routing_kernel<<<grid, NTHREADS, 0, stream>>>(x, wg, wn, noise, out);
}